// Round 3
// baseline (391.599 us; speedup 1.0000x reference)
//
#include <hip/hip_runtime.h>
#include <hip/hip_bf16.h>
#include <stdint.h>

typedef __hip_bfloat16 bf16;
typedef __attribute__((ext_vector_type(8))) short short8;
typedef __attribute__((ext_vector_type(4))) float f32x4;

#define MFMA16(a, b, c) __builtin_amdgcn_mfma_f32_16x16x32_bf16(a, b, c, 0, 0, 0)

#define BATCH 8
#define SEQ   1024
#define DEMB  1024
#define NH    16
#define DH    64
#define MTOT  (BATCH * SEQ)   // 8192

// ---------------------------------------------------------------------------
// dtype helpers: flag==1 -> input buffers are float32; flag==0 -> bf16.
// ---------------------------------------------------------------------------
__device__ __forceinline__ float rdf(const void* p, size_t idx, int isf) {
  if (isf) return ((const float*)p)[idx];
  return __bfloat162float(((const bf16*)p)[idx]);
}

// Kernel 0: detect input dtype from x. f32 normal data views as |v| < ~10;
// bf16-pair-packed words view as |v| > ~1e22 or NaN.
__global__ void detect_dtype(const unsigned int* __restrict__ xw, int* __restrict__ flag) {
  int lane = threadIdx.x;  // 64 threads
  float v = __uint_as_float(xw[lane]);
  bool isf32 = (fabsf(v) < 1e20f);  // NaN/Inf -> false
  unsigned long long m = __ballot(isf32);
  if (lane == 0) flag[0] = (__popcll(m) >= 32) ? 1 : 0;
}

// Kernel 0b: canonicalize x -> bf16 xc[8192][1024]. 8 elems/thread.
__global__ __launch_bounds__(256) void convert_x(
    const void* __restrict__ xin, bf16* __restrict__ xc, const int* __restrict__ flag) {
  const int isf = flag[0];
  size_t i = ((size_t)blockIdx.x * 256 + threadIdx.x) * 8;
  if (isf) {
    const float* xf = (const float*)xin;
    float4 a = *(const float4*)&xf[i];
    float4 b = *(const float4*)&xf[i + 4];
    bf16 o[8];
    o[0] = __float2bfloat16(a.x); o[1] = __float2bfloat16(a.y);
    o[2] = __float2bfloat16(a.z); o[3] = __float2bfloat16(a.w);
    o[4] = __float2bfloat16(b.x); o[5] = __float2bfloat16(b.y);
    o[6] = __float2bfloat16(b.z); o[7] = __float2bfloat16(b.w);
    *(int4*)&xc[i] = *(const int4*)&o[0];
  } else {
    *(int4*)&xc[i] = *(const int4*)&((const bf16*)xin)[i];
  }
}

// ---------------------------------------------------------------------------
// Kernel 1: permute+transpose w_qkv [1024][3072] (c = h*192 + dd*3 + j)
//           -> wt [3072][1024] rows c' = j*1024 + h*64 + dd, cols k.
//           Also permute bias into f32 bqp[c'].
// ---------------------------------------------------------------------------
__global__ __launch_bounds__(256) void permute_wqkv(
    const void* __restrict__ w, const void* __restrict__ b,
    bf16* __restrict__ wt, float* __restrict__ bqp, const int* __restrict__ flag) {
  __shared__ __attribute__((aligned(16))) bf16 ls[192][66];
  const int isf = flag[0];
  const int t = threadIdx.x;
  const int k0 = blockIdx.x * 64;
  const int h = blockIdx.y;
#pragma unroll
  for (int i = 0; i < 48; ++i) {
    int e = t + i * 256;
    int k = e / 192, c = e % 192;
    ls[c][k] = __float2bfloat16(rdf(w, (size_t)(k0 + k) * 3072 + h * 192 + c, isf));
  }
  if (blockIdx.x == 0 && t < 192) {
    int dd = t / 3, j = t % 3;
    bqp[j * 1024 + h * 64 + dd] = rdf(b, h * 192 + t, isf);
  }
  __syncthreads();
#pragma unroll
  for (int i = 0; i < 48; ++i) {
    int e = t + i * 256;
    int c = e / 64, k = e & 63;
    int dd = c / 3, j = c % 3;
    wt[(size_t)(j * 1024 + h * 64 + dd) * 1024 + k0 + k] = ls[c][k];
  }
}

// ---------------------------------------------------------------------------
// Kernel 2: transpose w_proj [1024][1024] -> wtp [n][k]
// ---------------------------------------------------------------------------
__global__ __launch_bounds__(256) void transpose_wp(
    const void* __restrict__ w, bf16* __restrict__ wt, const int* __restrict__ flag) {
  __shared__ __attribute__((aligned(16))) bf16 ls[64][66];
  const int isf = flag[0];
  const int t = threadIdx.x;
  const int r0 = blockIdx.y * 64;
  const int c0 = blockIdx.x * 64;
#pragma unroll
  for (int i = 0; i < 16; ++i) {
    int e = t + i * 256;
    int r = e >> 6, c = e & 63;
    ls[c][r] = __float2bfloat16(rdf(w, (size_t)(r0 + r) * 1024 + c0 + c, isf));
  }
  __syncthreads();
#pragma unroll
  for (int i = 0; i < 16; ++i) {
    int e = t + i * 256;
    int c = e >> 6, r = e & 63;
    wt[(size_t)(c0 + c) * 1024 + r0 + r] = ls[c][r];
  }
}

// ---------------------------------------------------------------------------
// Shared GEMM core: C[128x128] = A[m0..][1024] * Bt[n0..][1024]^T (bf16 in)
// ---------------------------------------------------------------------------
#define LK 56
__device__ __forceinline__ void gemm_core(
    const bf16* __restrict__ A, const bf16* __restrict__ Bt,
    int m0, int n0, f32x4 acc[4][4],
    bf16 lsA[128][LK], bf16 lsB[128][LK]) {
  const int t = threadIdx.x;
  const int lane = t & 63, w = t >> 6;
  const int quad = lane >> 4, col = lane & 15;
  const int wr = (w >> 1) * 64, wc = (w & 1) * 64;
  const int srow = t >> 2;
  const int skc = (t & 3) * 8;
  for (int kt = 0; kt < 1024; kt += 32) {
    int4 a0 = *(const int4*)&A[(size_t)(m0 + srow) * 1024 + kt + skc];
    int4 a1 = *(const int4*)&A[(size_t)(m0 + 64 + srow) * 1024 + kt + skc];
    int4 b0 = *(const int4*)&Bt[(size_t)(n0 + srow) * 1024 + kt + skc];
    int4 b1 = *(const int4*)&Bt[(size_t)(n0 + 64 + srow) * 1024 + kt + skc];
    __syncthreads();
    *(int4*)&lsA[srow][skc] = a0;
    *(int4*)&lsA[64 + srow][skc] = a1;
    *(int4*)&lsB[srow][skc] = b0;
    *(int4*)&lsB[64 + srow][skc] = b1;
    __syncthreads();
    short8 af[4], bfr[4];
#pragma unroll
    for (int i = 0; i < 4; ++i) af[i] = *(const short8*)&lsA[wr + i * 16 + col][quad * 8];
#pragma unroll
    for (int j = 0; j < 4; ++j) bfr[j] = *(const short8*)&lsB[wc + j * 16 + col][quad * 8];
#pragma unroll
    for (int i = 0; i < 4; ++i)
#pragma unroll
      for (int j = 0; j < 4; ++j)
        acc[i][j] = MFMA16(af[i], bfr[j], acc[i][j]);
  }
}

// ---------------------------------------------------------------------------
// Kernel 3: QKV GEMM. A = xc bf16. Scatters q,k -> [b][h][n][dd]; v -> [b][h][dd][n].
// ---------------------------------------------------------------------------
__global__ __launch_bounds__(256) void gemm_qkv(
    const bf16* __restrict__ A, const bf16* __restrict__ Bt,
    const float* __restrict__ bias,
    bf16* __restrict__ qb, bf16* __restrict__ kb, bf16* __restrict__ vb) {
  __shared__ __attribute__((aligned(16))) bf16 lsA[128][LK];
  __shared__ __attribute__((aligned(16))) bf16 lsB[128][LK];
  const int t = threadIdx.x;
  const int lane = t & 63, w = t >> 6;
  const int quad = lane >> 4, col = lane & 15;
  const int wr = (w >> 1) * 64, wc = (w & 1) * 64;
  const int m0 = blockIdx.y * 128;
  const int n0 = blockIdx.x * 128;
  f32x4 acc[4][4];
  const f32x4 zero = {0.f, 0.f, 0.f, 0.f};
#pragma unroll
  for (int i = 0; i < 4; ++i)
#pragma unroll
    for (int j = 0; j < 4; ++j) acc[i][j] = zero;

  gemm_core(A, Bt, m0, n0, acc, lsA, lsB);

  const int jj = n0 >> 10;
#pragma unroll
  for (int i = 0; i < 4; ++i) {
    int rbase = m0 + wr + i * 16 + quad * 4;
#pragma unroll
    for (int j = 0; j < 4; ++j) {
      int c = n0 + wc + j * 16 + col;
      int cc = c & 1023;
      int h = cc >> 6, dd = cc & 63;
      float bv = bias[c];
#pragma unroll
      for (int r = 0; r < 4; ++r) {
        int m = rbase + r;
        int bb = m >> 10, n = m & 1023;
        bf16 val = __float2bfloat16(acc[i][j][r] + bv);
        size_t bhq = (size_t)(bb * NH + h);
        if (jj == 0)      qb[(bhq * 1024 + n) * 64 + dd] = val;
        else if (jj == 1) kb[(bhq * 1024 + n) * 64 + dd] = val;
        else              vb[(bhq * 64 + dd) * 1024 + n] = val;
      }
    }
  }
}

// ---------------------------------------------------------------------------
// Kernel 4: flash attention. grid (16 q-tiles of 64, 128 b*h), 4 waves.
// Softmax scaled AFTER normalization by 1/32 (1/sqrt(1024)). Output bf16.
// ---------------------------------------------------------------------------
__global__ __launch_bounds__(256) void attn(
    const bf16* __restrict__ qb, const bf16* __restrict__ kb,
    const bf16* __restrict__ vb, bf16* __restrict__ ob) {
  const int t = threadIdx.x, lane = t & 63, w = t >> 6;
  const int quad = lane >> 4, col = lane & 15;
  const int bh = blockIdx.y;
  const int bat = bh >> 4, h = bh & 15;
  const int q0 = blockIdx.x * 64;

  __shared__ __attribute__((aligned(16))) bf16 lsQ[64][72];
  __shared__ __attribute__((aligned(16))) bf16 lsV[64][136];
  __shared__ __attribute__((aligned(16))) char lsKP[128 * 72 * 2];
  bf16(*lsK)[72] = (bf16(*)[72])lsKP;
  bf16(*lsP)[136] = (bf16(*)[136])lsKP;

  const bf16* qp = qb + (size_t)bh * (1024 * 64);
  const bf16* kp = kb + (size_t)bh * (1024 * 64);
  const bf16* vp = vb + (size_t)bh * (64 * 1024);

#pragma unroll
  for (int i = 0; i < 2; ++i) {
    int e = t + i * 256;
    int r = e >> 3, kc = (e & 7) * 8;
    *(int4*)&lsQ[r][kc] = *(const int4*)&qp[(size_t)(q0 + r) * 64 + kc];
  }

  float mrow[4], lrow[4];
  f32x4 po[4];
  const f32x4 zero = {0.f, 0.f, 0.f, 0.f};
#pragma unroll
  for (int r = 0; r < 4; ++r) { mrow[r] = -1e30f; lrow[r] = 0.f; }
#pragma unroll
  for (int tj = 0; tj < 4; ++tj) po[tj] = zero;

  for (int kt = 0; kt < 1024; kt += 128) {
    __syncthreads();
#pragma unroll
    for (int i = 0; i < 4; ++i) {
      int e = t + i * 256;
      int r = e >> 3, kc = (e & 7) * 8;
      *(int4*)&lsK[r][kc] = *(const int4*)&kp[(size_t)(kt + r) * 64 + kc];
    }
#pragma unroll
    for (int i = 0; i < 4; ++i) {
      int e = t + i * 256;
      int r = e >> 4, cc = (e & 15) * 8;
      *(int4*)&lsV[r][cc] = *(const int4*)&vp[(size_t)r * 1024 + kt + cc];
    }
    __syncthreads();

    f32x4 s[8];
#pragma unroll
    for (int tj = 0; tj < 8; ++tj) s[tj] = zero;
#pragma unroll
    for (int kk = 0; kk < 2; ++kk) {
      short8 aq = *(const short8*)&lsQ[w * 16 + col][kk * 32 + quad * 8];
#pragma unroll
      for (int tj = 0; tj < 8; ++tj) {
        short8 bk = *(const short8*)&lsK[tj * 16 + col][kk * 32 + quad * 8];
        s[tj] = MFMA16(aq, bk, s[tj]);
      }
    }

#pragma unroll
    for (int r = 0; r < 4; ++r) {
      float mx = s[0][r];
#pragma unroll
      for (int tj = 1; tj < 8; ++tj) mx = fmaxf(mx, s[tj][r]);
      mx = fmaxf(mx, __shfl_xor(mx, 1));
      mx = fmaxf(mx, __shfl_xor(mx, 2));
      mx = fmaxf(mx, __shfl_xor(mx, 4));
      mx = fmaxf(mx, __shfl_xor(mx, 8));
      float mnew = fmaxf(mrow[r], mx);
      float alpha = __expf(mrow[r] - mnew);
      mrow[r] = mnew;
      float lsum = 0.f;
#pragma unroll
      for (int tj = 0; tj < 8; ++tj) {
        float p = __expf(s[tj][r] - mnew);
        s[tj][r] = p;
        lsum += p;
      }
      lsum += __shfl_xor(lsum, 1);
      lsum += __shfl_xor(lsum, 2);
      lsum += __shfl_xor(lsum, 4);
      lsum += __shfl_xor(lsum, 8);
      lrow[r] = lrow[r] * alpha + lsum;
#pragma unroll
      for (int tj = 0; tj < 4; ++tj) po[tj][r] *= alpha;
    }

    __syncthreads();
#pragma unroll
    for (int tj = 0; tj < 8; ++tj)
#pragma unroll
      for (int r = 0; r < 4; ++r)
        lsP[w * 16 + quad * 4 + r][tj * 16 + col] = __float2bfloat16(s[tj][r]);
    __syncthreads();

#pragma unroll
    for (int kk = 0; kk < 4; ++kk) {
      short8 ap = *(const short8*)&lsP[w * 16 + col][kk * 32 + quad * 8];
#pragma unroll
      for (int tj = 0; tj < 4; ++tj) {
        short8 bv = *(const short8*)&lsV[tj * 16 + col][kk * 32 + quad * 8];
        po[tj] = MFMA16(ap, bv, po[tj]);
      }
    }
  }

  bf16* op = ob + (size_t)bat * 1024 * 1024 + h * 64;
#pragma unroll
  for (int tj = 0; tj < 4; ++tj)
#pragma unroll
    for (int r = 0; r < 4; ++r) {
      int q = q0 + w * 16 + quad * 4 + r;
      int dd = tj * 16 + col;
      float v = po[tj][r] / (lrow[r] * 32.0f);
      op[(size_t)q * 1024 + dd] = __float2bfloat16(v);
    }
}

// ---------------------------------------------------------------------------
// Kernel 5: output projection. A = att bf16, Bt = wtp. OUTPUT: float32.
// ---------------------------------------------------------------------------
__global__ __launch_bounds__(256) void gemm_proj(
    const bf16* __restrict__ A, const bf16* __restrict__ Bt,
    const void* __restrict__ bias, float* __restrict__ out,
    const int* __restrict__ flag) {
  __shared__ __attribute__((aligned(16))) bf16 lsA[128][LK];
  __shared__ __attribute__((aligned(16))) bf16 lsB[128][LK];
  const int isf = flag[0];
  const int t = threadIdx.x;
  const int lane = t & 63, w = t >> 6;
  const int quad = lane >> 4, col = lane & 15;
  const int wr = (w >> 1) * 64, wc = (w & 1) * 64;
  const int m0 = blockIdx.y * 128;
  const int n0 = blockIdx.x * 128;
  f32x4 acc[4][4];
  const f32x4 zero = {0.f, 0.f, 0.f, 0.f};
#pragma unroll
  for (int i = 0; i < 4; ++i)
#pragma unroll
    for (int j = 0; j < 4; ++j) acc[i][j] = zero;

  gemm_core(A, Bt, m0, n0, acc, lsA, lsB);

#pragma unroll
  for (int i = 0; i < 4; ++i) {
    int rbase = m0 + wr + i * 16 + quad * 4;
#pragma unroll
    for (int j = 0; j < 4; ++j) {
      int c = n0 + wc + j * 16 + col;
      float bv = rdf(bias, c, isf);
#pragma unroll
      for (int r = 0; r < 4; ++r)
        out[(size_t)(rbase + r) * 1024 + c] = acc[i][j][r] + bv;
    }
  }
}

// ---------------------------------------------------------------------------
// Launcher. ws layout (75.5 MB):
//   wt_qkv 6MB | bqp 12KB | wtp 2MB | xc/att 16MB | q 16MB | k 16MB | v 16MB | flag
// ---------------------------------------------------------------------------
extern "C" void kernel_launch(void* const* d_in, const int* in_sizes, int n_in,
                              void* d_out, int out_size, void* d_ws, size_t ws_size,
                              hipStream_t stream) {
  const void* x      = d_in[0];
  const void* w_qkv  = d_in[1];
  const void* b_qkv  = d_in[2];
  const void* w_proj = d_in[3];
  const void* b_proj = d_in[4];
  float* out = (float*)d_out;

  char* ws = (char*)d_ws;
  bf16*  wt_qkv = (bf16*)(ws);
  float* bqp    = (float*)(ws + 6291456);
  bf16*  wtp    = (bf16*)(ws + 6303744);
  bf16*  xc     = (bf16*)(ws + 8400896);    // reused as att after gemm_qkv
  bf16*  q_buf  = (bf16*)(ws + 25178112);
  bf16*  k_buf  = (bf16*)(ws + 41955328);
  bf16*  v_buf  = (bf16*)(ws + 58732544);
  int*   flag   = (int*)(ws + 75509760);
  bf16*  att    = xc;

  detect_dtype<<<1, 64, 0, stream>>>((const unsigned int*)x, flag);
  convert_x<<<4096, 256, 0, stream>>>(x, xc, flag);
  permute_wqkv<<<dim3(16, 16), 256, 0, stream>>>(w_qkv, b_qkv, wt_qkv, bqp, flag);
  transpose_wp<<<dim3(16, 16), 256, 0, stream>>>(w_proj, wtp, flag);
  gemm_qkv<<<dim3(24, 64), 256, 0, stream>>>(xc, wt_qkv, bqp, q_buf, k_buf, v_buf);
  attn<<<dim3(16, 128), 256, 0, stream>>>(q_buf, k_buf, v_buf, att);
  gemm_proj<<<dim3(8, 64), 256, 0, stream>>>(att, wtp, b_proj, out, flag);
}

// Round 4
// 326.250 us; speedup vs baseline: 1.2003x; 1.2003x over previous
//
#include <hip/hip_runtime.h>
#include <hip/hip_bf16.h>
#include <stdint.h>

typedef __hip_bfloat16 bf16;
typedef __attribute__((ext_vector_type(8))) short short8;
typedef __attribute__((ext_vector_type(4))) float f32x4;
typedef __attribute__((ext_vector_type(16))) float f32x16;

#define MFMA16(a, b, c) __builtin_amdgcn_mfma_f32_16x16x32_bf16(a, b, c, 0, 0, 0)
#define MFMA32(a, b, c) __builtin_amdgcn_mfma_f32_32x32x16_bf16(a, b, c, 0, 0, 0)

#define BATCH 8
#define SEQ   1024
#define DEMB  1024
#define NH    16
#define DH    64
#define MTOT  (BATCH * SEQ)   // 8192

// ---------------------------------------------------------------------------
// dtype helpers: flag==1 -> input buffers are float32; flag==0 -> bf16.
// ---------------------------------------------------------------------------
__device__ __forceinline__ float rdf(const void* p, size_t idx, int isf) {
  if (isf) return ((const float*)p)[idx];
  return __bfloat162float(((const bf16*)p)[idx]);
}

// pack two f32 -> bf16x2 dword (RTN via __float2bfloat16)
__device__ __forceinline__ unsigned int pk2(float a, float b) {
  unsigned short ua = __bfloat16_as_ushort(__float2bfloat16(a));
  unsigned short ub = __bfloat16_as_ushort(__float2bfloat16(b));
  return (unsigned int)ua | ((unsigned int)ub << 16);
}

union U4S8 { uint4 u; short8 s; };

// Kernel 0: detect input dtype from x.
__global__ void detect_dtype(const unsigned int* __restrict__ xw, int* __restrict__ flag) {
  int lane = threadIdx.x;  // 64 threads
  float v = __uint_as_float(xw[lane]);
  bool isf32 = (fabsf(v) < 1e20f);  // NaN/Inf -> false
  unsigned long long m = __ballot(isf32);
  if (lane == 0) flag[0] = (__popcll(m) >= 32) ? 1 : 0;
}

// Kernel 0b: canonicalize x -> bf16 xc[8192][1024]. 8 elems/thread.
__global__ __launch_bounds__(256) void convert_x(
    const void* __restrict__ xin, bf16* __restrict__ xc, const int* __restrict__ flag) {
  const int isf = flag[0];
  size_t i = ((size_t)blockIdx.x * 256 + threadIdx.x) * 8;
  if (isf) {
    const float* xf = (const float*)xin;
    float4 a = *(const float4*)&xf[i];
    float4 b = *(const float4*)&xf[i + 4];
    bf16 o[8];
    o[0] = __float2bfloat16(a.x); o[1] = __float2bfloat16(a.y);
    o[2] = __float2bfloat16(a.z); o[3] = __float2bfloat16(a.w);
    o[4] = __float2bfloat16(b.x); o[5] = __float2bfloat16(b.y);
    o[6] = __float2bfloat16(b.z); o[7] = __float2bfloat16(b.w);
    *(int4*)&xc[i] = *(const int4*)&o[0];
  } else {
    *(int4*)&xc[i] = *(const int4*)&((const bf16*)xin)[i];
  }
}

// ---------------------------------------------------------------------------
// Kernel 1: permute+transpose w_qkv -> wt [3072][1024]; bias -> f32 bqp.
// ---------------------------------------------------------------------------
__global__ __launch_bounds__(256) void permute_wqkv(
    const void* __restrict__ w, const void* __restrict__ b,
    bf16* __restrict__ wt, float* __restrict__ bqp, const int* __restrict__ flag) {
  __shared__ __attribute__((aligned(16))) bf16 ls[192][66];
  const int isf = flag[0];
  const int t = threadIdx.x;
  const int k0 = blockIdx.x * 64;
  const int h = blockIdx.y;
#pragma unroll
  for (int i = 0; i < 48; ++i) {
    int e = t + i * 256;
    int k = e / 192, c = e % 192;
    ls[c][k] = __float2bfloat16(rdf(w, (size_t)(k0 + k) * 3072 + h * 192 + c, isf));
  }
  if (blockIdx.x == 0 && t < 192) {
    int dd = t / 3, j = t % 3;
    bqp[j * 1024 + h * 64 + dd] = rdf(b, h * 192 + t, isf);
  }
  __syncthreads();
#pragma unroll
  for (int i = 0; i < 48; ++i) {
    int e = t + i * 256;
    int c = e / 64, k = e & 63;
    int dd = c / 3, j = c % 3;
    wt[(size_t)(j * 1024 + h * 64 + dd) * 1024 + k0 + k] = ls[c][k];
  }
}

// ---------------------------------------------------------------------------
// Kernel 2: transpose w_proj [1024][1024] -> wtp [n][k]
// ---------------------------------------------------------------------------
__global__ __launch_bounds__(256) void transpose_wp(
    const void* __restrict__ w, bf16* __restrict__ wt, const int* __restrict__ flag) {
  __shared__ __attribute__((aligned(16))) bf16 ls[64][66];
  const int isf = flag[0];
  const int t = threadIdx.x;
  const int r0 = blockIdx.y * 64;
  const int c0 = blockIdx.x * 64;
#pragma unroll
  for (int i = 0; i < 16; ++i) {
    int e = t + i * 256;
    int r = e >> 6, c = e & 63;
    ls[c][r] = __float2bfloat16(rdf(w, (size_t)(r0 + r) * 1024 + c0 + c, isf));
  }
  __syncthreads();
#pragma unroll
  for (int i = 0; i < 16; ++i) {
    int e = t + i * 256;
    int c = e >> 6, r = e & 63;
    wt[(size_t)(c0 + c) * 1024 + r0 + r] = ls[c][r];
  }
}

// ---------------------------------------------------------------------------
// Shared GEMM core: C[128x128] = A[m0..][1024] * Bt[n0..][1024]^T (bf16 in)
// ---------------------------------------------------------------------------
#define LK 56
__device__ __forceinline__ void gemm_core(
    const bf16* __restrict__ A, const bf16* __restrict__ Bt,
    int m0, int n0, f32x4 acc[4][4],
    bf16 lsA[128][LK], bf16 lsB[128][LK]) {
  const int t = threadIdx.x;
  const int lane = t & 63, w = t >> 6;
  const int quad = lane >> 4, col = lane & 15;
  const int wr = (w >> 1) * 64, wc = (w & 1) * 64;
  const int srow = t >> 2;
  const int skc = (t & 3) * 8;
  for (int kt = 0; kt < 1024; kt += 32) {
    int4 a0 = *(const int4*)&A[(size_t)(m0 + srow) * 1024 + kt + skc];
    int4 a1 = *(const int4*)&A[(size_t)(m0 + 64 + srow) * 1024 + kt + skc];
    int4 b0 = *(const int4*)&Bt[(size_t)(n0 + srow) * 1024 + kt + skc];
    int4 b1 = *(const int4*)&Bt[(size_t)(n0 + 64 + srow) * 1024 + kt + skc];
    __syncthreads();
    *(int4*)&lsA[srow][skc] = a0;
    *(int4*)&lsA[64 + srow][skc] = a1;
    *(int4*)&lsB[srow][skc] = b0;
    *(int4*)&lsB[64 + srow][skc] = b1;
    __syncthreads();
    short8 af[4], bfr[4];
#pragma unroll
    for (int i = 0; i < 4; ++i) af[i] = *(const short8*)&lsA[wr + i * 16 + col][quad * 8];
#pragma unroll
    for (int j = 0; j < 4; ++j) bfr[j] = *(const short8*)&lsB[wc + j * 16 + col][quad * 8];
#pragma unroll
    for (int i = 0; i < 4; ++i)
#pragma unroll
      for (int j = 0; j < 4; ++j)
        acc[i][j] = MFMA16(af[i], bfr[j], acc[i][j]);
  }
}

// ---------------------------------------------------------------------------
// Kernel 3: QKV GEMM. A = xc bf16. Scatters q,k -> [b][h][n][dd]; v -> [b][h][dd][n].
// ---------------------------------------------------------------------------
__global__ __launch_bounds__(256) void gemm_qkv(
    const bf16* __restrict__ A, const bf16* __restrict__ Bt,
    const float* __restrict__ bias,
    bf16* __restrict__ qb, bf16* __restrict__ kb, bf16* __restrict__ vb) {
  __shared__ __attribute__((aligned(16))) bf16 lsA[128][LK];
  __shared__ __attribute__((aligned(16))) bf16 lsB[128][LK];
  const int t = threadIdx.x;
  const int lane = t & 63, w = t >> 6;
  const int quad = lane >> 4, col = lane & 15;
  const int wr = (w >> 1) * 64, wc = (w & 1) * 64;
  const int m0 = blockIdx.y * 128;
  const int n0 = blockIdx.x * 128;
  f32x4 acc[4][4];
  const f32x4 zero = {0.f, 0.f, 0.f, 0.f};
#pragma unroll
  for (int i = 0; i < 4; ++i)
#pragma unroll
    for (int j = 0; j < 4; ++j) acc[i][j] = zero;

  gemm_core(A, Bt, m0, n0, acc, lsA, lsB);

  const int jj = n0 >> 10;
#pragma unroll
  for (int i = 0; i < 4; ++i) {
    int rbase = m0 + wr + i * 16 + quad * 4;
#pragma unroll
    for (int j = 0; j < 4; ++j) {
      int c = n0 + wc + j * 16 + col;
      int cc = c & 1023;
      int h = cc >> 6, dd = cc & 63;
      float bv = bias[c];
#pragma unroll
      for (int r = 0; r < 4; ++r) {
        int m = rbase + r;
        int bb = m >> 10, n = m & 1023;
        bf16 val = __float2bfloat16(acc[i][j][r] + bv);
        size_t bhq = (size_t)(bb * NH + h);
        if (jj == 0)      qb[(bhq * 1024 + n) * 64 + dd] = val;
        else if (jj == 1) kb[(bhq * 1024 + n) * 64 + dd] = val;
        else              vb[(bhq * 64 + dd) * 1024 + n] = val;
      }
    }
  }
}

// ---------------------------------------------------------------------------
// Kernel 4 v2: flash attention with 32x32x16 MFMA, S^T/O^T formulation.
// grid (8 q-tiles of 128, 128 bh), 256 thr = 4 waves, wave w owns q-band w*32.
// S^T = K*Q^T  (C-layout col = q  -> per-lane scalar softmax state)
// O^T = V^T*P^T (P^T fragment built in-register via one shfl_xor(32) exchange)
// K-tile 64. LDS = lsK + lsV = 18432 B. No P round-trip, 2 barriers/iter.
// ---------------------------------------------------------------------------
__global__ __launch_bounds__(256, 4) void attn(
    const bf16* __restrict__ qb, const bf16* __restrict__ kb,
    const bf16* __restrict__ vb, bf16* __restrict__ ob) {
  const int t = threadIdx.x, lane = t & 63, w = t >> 6;
  const int q5 = lane & 31, half = lane >> 5;
  const int bh = blockIdx.y;
  const int bat = bh >> 4, h = bh & 15;
  const int q0 = blockIdx.x * 128;
  const int qrow = q0 + w * 32 + q5;   // this lane's q row (0..1023 within bh)

  __shared__ __attribute__((aligned(16))) bf16 lsK[64][72];  // 9216 B
  __shared__ __attribute__((aligned(16))) bf16 lsV[64][72];  // 9216 B

  const bf16* qp = qb + (size_t)bh * (1024 * 64);
  const bf16* kp = kb + (size_t)bh * (1024 * 64);
  const bf16* vp = vb + (size_t)bh * (64 * 1024);  // [dv][n]

  // Q fragments in registers: B-operand of S^T = K*Q^T.
  // B[n=q5][k = kk*16 + half*8 + j]
  short8 bq[4];
#pragma unroll
  for (int kk = 0; kk < 4; ++kk)
    bq[kk] = *(const short8*)&qp[(size_t)qrow * 64 + kk * 16 + half * 8];

  float m_run = -1e30f, l_run = 0.f;
  f32x16 po[2];
#pragma unroll
  for (int r = 0; r < 16; ++r) { po[0][r] = 0.f; po[1][r] = 0.f; }

  const int sr = t >> 3;        // 0..31
  const int sc = (t & 7) * 8;   // 0..56

  for (int kt = 0; kt < 1024; kt += 64) {
    // stage K [64][64] and V^T [64][64] (global loads issued before barrier)
    int4 g0 = *(const int4*)&kp[(size_t)(kt + sr) * 64 + sc];
    int4 g1 = *(const int4*)&kp[(size_t)(kt + 32 + sr) * 64 + sc];
    int4 g2 = *(const int4*)&vp[(size_t)sr * 1024 + kt + sc];
    int4 g3 = *(const int4*)&vp[(size_t)(32 + sr) * 1024 + kt + sc];
    __syncthreads();   // prior iter's lsK/lsV readers done
    *(int4*)&lsK[sr][sc] = g0;
    *(int4*)&lsK[32 + sr][sc] = g1;
    *(int4*)&lsV[sr][sc] = g2;
    *(int4*)&lsV[32 + sr][sc] = g3;
    __syncthreads();

    // S^T = K * Q^T : st[tj] covers kn rows [tj*32, tj*32+32), col = q5 (my q)
    f32x16 st[2];
#pragma unroll
    for (int r = 0; r < 16; ++r) { st[0][r] = 0.f; st[1][r] = 0.f; }
#pragma unroll
    for (int kk = 0; kk < 4; ++kk) {
#pragma unroll
      for (int tj = 0; tj < 2; ++tj) {
        short8 ak = *(const short8*)&lsK[tj * 32 + q5][kk * 16 + half * 8];
        st[tj] = MFMA32(ak, bq[kk], st[tj]);
      }
    }

    // online softmax: all 32 st values share q = qrow; other 32 kn values of
    // this iter live in the half-partner lane -> 1 shuffle per reduction.
    float smax = st[0][0];
#pragma unroll
    for (int r = 1; r < 16; ++r) smax = fmaxf(smax, st[0][r]);
#pragma unroll
    for (int r = 0; r < 16; ++r) smax = fmaxf(smax, st[1][r]);
    smax = fmaxf(smax, __shfl_xor(smax, 32));
    float mnew = fmaxf(m_run, smax);
    float alpha = __expf(m_run - mnew);
    m_run = mnew;
    float lsum = 0.f;
#pragma unroll
    for (int tj = 0; tj < 2; ++tj)
#pragma unroll
      for (int r = 0; r < 16; ++r) {
        float p = __expf(st[tj][r] - mnew);
        st[tj][r] = p;
        lsum += p;
      }
    lsum += __shfl_xor(lsum, 32);
    l_run = l_run * alpha + lsum;
#pragma unroll
    for (int r = 0; r < 16; ++r) { po[0][r] *= alpha; po[1][r] *= alpha; }

    // O^T += V^T * P^T. B-operand (P^T) built in-register:
    // lane owns m = [4*half, 4*half+4) of every kn-8-block nb at
    // st[nb>>2][4*(nb&3) + 0..3]; partner owns the other 4 -> 1 shfl_xor(32).
#pragma unroll
    for (int kk2 = 0; kk2 < 4; ++kk2) {
      const int nbA = 2 * kk2, nbB = 2 * kk2 + 1;
      unsigned int a0 = pk2(st[nbA >> 2][4 * (nbA & 3) + 0], st[nbA >> 2][4 * (nbA & 3) + 1]);
      unsigned int a1 = pk2(st[nbA >> 2][4 * (nbA & 3) + 2], st[nbA >> 2][4 * (nbA & 3) + 3]);
      unsigned int b0 = pk2(st[nbB >> 2][4 * (nbB & 3) + 0], st[nbB >> 2][4 * (nbB & 3) + 1]);
      unsigned int b1 = pk2(st[nbB >> 2][4 * (nbB & 3) + 2], st[nbB >> 2][4 * (nbB & 3) + 3]);
      // half 0 consumes block A (sends B); half 1 consumes block B (sends A)
      unsigned int s0 = half ? a0 : b0;
      unsigned int s1 = half ? a1 : b1;
      unsigned int r0 = (unsigned int)__shfl_xor((int)s0, 32);
      unsigned int r1 = (unsigned int)__shfl_xor((int)s1, 32);
      U4S8 fr;
      fr.u.x = half ? r0 : a0;   // j0,j1  (m 0..1 of my block)
      fr.u.y = half ? r1 : a1;   // j2,j3
      fr.u.z = half ? b0 : r0;   // j4,j5  (m 4..5)
      fr.u.w = half ? b1 : r1;   // j6,j7
#pragma unroll
      for (int ti = 0; ti < 2; ++ti) {
        short8 av = *(const short8*)&lsV[ti * 32 + q5][kk2 * 16 + half * 8];
        po[ti] = MFMA32(av, fr.s, po[ti]);
      }
    }
  }

  // epilogue: O^T[dv-pattern][q=lane]: att[(bat*1024+qrow)*1024 + h*64 + dv]
  float inv = 1.0f / (l_run * 32.0f);
  bf16* op = ob + ((size_t)(bat * 1024 + qrow)) * 1024 + h * 64;
#pragma unroll
  for (int ti = 0; ti < 2; ++ti)
#pragma unroll
    for (int g = 0; g < 4; ++g) {
      unsigned int lo = pk2(po[ti][4 * g + 0] * inv, po[ti][4 * g + 1] * inv);
      unsigned int hi = pk2(po[ti][4 * g + 2] * inv, po[ti][4 * g + 3] * inv);
      uint2 u = make_uint2(lo, hi);
      *(uint2*)&op[ti * 32 + g * 8 + half * 4] = u;
    }
}

// ---------------------------------------------------------------------------
// Kernel 5: output projection. A = att bf16, Bt = wtp. OUTPUT: float32.
// ---------------------------------------------------------------------------
__global__ __launch_bounds__(256) void gemm_proj(
    const bf16* __restrict__ A, const bf16* __restrict__ Bt,
    const void* __restrict__ bias, float* __restrict__ out,
    const int* __restrict__ flag) {
  __shared__ __attribute__((aligned(16))) bf16 lsA[128][LK];
  __shared__ __attribute__((aligned(16))) bf16 lsB[128][LK];
  const int isf = flag[0];
  const int t = threadIdx.x;
  const int lane = t & 63, w = t >> 6;
  const int quad = lane >> 4, col = lane & 15;
  const int wr = (w >> 1) * 64, wc = (w & 1) * 64;
  const int m0 = blockIdx.y * 128;
  const int n0 = blockIdx.x * 128;
  f32x4 acc[4][4];
  const f32x4 zero = {0.f, 0.f, 0.f, 0.f};
#pragma unroll
  for (int i = 0; i < 4; ++i)
#pragma unroll
    for (int j = 0; j < 4; ++j) acc[i][j] = zero;

  gemm_core(A, Bt, m0, n0, acc, lsA, lsB);

#pragma unroll
  for (int i = 0; i < 4; ++i) {
    int rbase = m0 + wr + i * 16 + quad * 4;
#pragma unroll
    for (int j = 0; j < 4; ++j) {
      int c = n0 + wc + j * 16 + col;
      float bv = rdf(bias, c, isf);
#pragma unroll
      for (int r = 0; r < 4; ++r)
        out[(size_t)(rbase + r) * 1024 + c] = acc[i][j][r] + bv;
    }
  }
}

// ---------------------------------------------------------------------------
// Launcher. ws layout (75.5 MB):
//   wt_qkv 6MB | bqp 12KB | wtp 2MB | xc/att 16MB | q 16MB | k 16MB | v 16MB | flag
// ---------------------------------------------------------------------------
extern "C" void kernel_launch(void* const* d_in, const int* in_sizes, int n_in,
                              void* d_out, int out_size, void* d_ws, size_t ws_size,
                              hipStream_t stream) {
  const void* x      = d_in[0];
  const void* w_qkv  = d_in[1];
  const void* b_qkv  = d_in[2];
  const void* w_proj = d_in[3];
  const void* b_proj = d_in[4];
  float* out = (float*)d_out;

  char* ws = (char*)d_ws;
  bf16*  wt_qkv = (bf16*)(ws);
  float* bqp    = (float*)(ws + 6291456);
  bf16*  wtp    = (bf16*)(ws + 6303744);
  bf16*  xc     = (bf16*)(ws + 8400896);    // reused as att after gemm_qkv
  bf16*  q_buf  = (bf16*)(ws + 25178112);
  bf16*  k_buf  = (bf16*)(ws + 41955328);
  bf16*  v_buf  = (bf16*)(ws + 58732544);
  int*   flag   = (int*)(ws + 75509760);
  bf16*  att    = xc;

  detect_dtype<<<1, 64, 0, stream>>>((const unsigned int*)x, flag);
  convert_x<<<4096, 256, 0, stream>>>(x, xc, flag);
  permute_wqkv<<<dim3(16, 16), 256, 0, stream>>>(w_qkv, b_qkv, wt_qkv, bqp, flag);
  transpose_wp<<<dim3(16, 16), 256, 0, stream>>>(w_proj, wtp, flag);
  gemm_qkv<<<dim3(24, 64), 256, 0, stream>>>(xc, wt_qkv, bqp, q_buf, k_buf, v_buf);
  attn<<<dim3(8, 128), 256, 0, stream>>>(q_buf, k_buf, v_buf, att);
  gemm_proj<<<dim3(8, 64), 256, 0, stream>>>(att, wtp, b_proj, out, flag);
}

// Round 5
// 304.977 us; speedup vs baseline: 1.2840x; 1.0698x over previous
//
#include <hip/hip_runtime.h>
#include <hip/hip_bf16.h>
#include <stdint.h>

typedef __hip_bfloat16 bf16;
typedef __attribute__((ext_vector_type(8))) short short8;
typedef __attribute__((ext_vector_type(4))) float f32x4;
typedef __attribute__((ext_vector_type(16))) float f32x16;

#define MFMA16(a, b, c) __builtin_amdgcn_mfma_f32_16x16x32_bf16(a, b, c, 0, 0, 0)
#define MFMA32(a, b, c) __builtin_amdgcn_mfma_f32_32x32x16_bf16(a, b, c, 0, 0, 0)

#define BATCH 8
#define SEQ   1024
#define DEMB  1024
#define NH    16
#define DH    64
#define MTOT  (BATCH * SEQ)   // 8192

// ---------------------------------------------------------------------------
// dtype helpers: flag==1 -> input buffers are float32; flag==0 -> bf16.
// ---------------------------------------------------------------------------
__device__ __forceinline__ float rdf(const void* p, size_t idx, int isf) {
  if (isf) return ((const float*)p)[idx];
  return __bfloat162float(((const bf16*)p)[idx]);
}

// pack two f32 -> bf16x2 dword
__device__ __forceinline__ unsigned int pk2(float a, float b) {
  unsigned short ua = __bfloat16_as_ushort(__float2bfloat16(a));
  unsigned short ub = __bfloat16_as_ushort(__float2bfloat16(b));
  return (unsigned int)ua | ((unsigned int)ub << 16);
}

union U4S8 { uint4 u; short8 s; };

// async global->LDS, 16B per lane; lds base wave-uniform (HW adds lane*16)
__device__ __forceinline__ void gload16(const bf16* g, bf16* l) {
  __builtin_amdgcn_global_load_lds(
      (const __attribute__((address_space(1))) void*)g,
      (__attribute__((address_space(3))) void*)l, 16, 0, 0);
}

// Kernel 0: detect input dtype from x.
__global__ void detect_dtype(const unsigned int* __restrict__ xw, int* __restrict__ flag) {
  int lane = threadIdx.x;  // 64 threads
  float v = __uint_as_float(xw[lane]);
  bool isf32 = (fabsf(v) < 1e20f);  // NaN/Inf -> false
  unsigned long long m = __ballot(isf32);
  if (lane == 0) flag[0] = (__popcll(m) >= 32) ? 1 : 0;
}

// Kernel 0b: canonicalize x -> bf16 xc[8192][1024]. 8 elems/thread.
__global__ __launch_bounds__(256) void convert_x(
    const void* __restrict__ xin, bf16* __restrict__ xc, const int* __restrict__ flag) {
  const int isf = flag[0];
  size_t i = ((size_t)blockIdx.x * 256 + threadIdx.x) * 8;
  if (isf) {
    const float* xf = (const float*)xin;
    float4 a = *(const float4*)&xf[i];
    float4 b = *(const float4*)&xf[i + 4];
    bf16 o[8];
    o[0] = __float2bfloat16(a.x); o[1] = __float2bfloat16(a.y);
    o[2] = __float2bfloat16(a.z); o[3] = __float2bfloat16(a.w);
    o[4] = __float2bfloat16(b.x); o[5] = __float2bfloat16(b.y);
    o[6] = __float2bfloat16(b.z); o[7] = __float2bfloat16(b.w);
    *(int4*)&xc[i] = *(const int4*)&o[0];
  } else {
    *(int4*)&xc[i] = *(const int4*)&((const bf16*)xin)[i];
  }
}

// ---------------------------------------------------------------------------
// Kernel 1: permute+transpose w_qkv -> wt [3072][1024]; bias -> f32 bqp.
// ---------------------------------------------------------------------------
__global__ __launch_bounds__(256) void permute_wqkv(
    const void* __restrict__ w, const void* __restrict__ b,
    bf16* __restrict__ wt, float* __restrict__ bqp, const int* __restrict__ flag) {
  __shared__ __attribute__((aligned(16))) bf16 ls[192][66];
  const int isf = flag[0];
  const int t = threadIdx.x;
  const int k0 = blockIdx.x * 64;
  const int h = blockIdx.y;
#pragma unroll
  for (int i = 0; i < 48; ++i) {
    int e = t + i * 256;
    int k = e / 192, c = e % 192;
    ls[c][k] = __float2bfloat16(rdf(w, (size_t)(k0 + k) * 3072 + h * 192 + c, isf));
  }
  if (blockIdx.x == 0 && t < 192) {
    int dd = t / 3, j = t % 3;
    bqp[j * 1024 + h * 64 + dd] = rdf(b, h * 192 + t, isf);
  }
  __syncthreads();
#pragma unroll
  for (int i = 0; i < 48; ++i) {
    int e = t + i * 256;
    int c = e / 64, k = e & 63;
    int dd = c / 3, j = c % 3;
    wt[(size_t)(j * 1024 + h * 64 + dd) * 1024 + k0 + k] = ls[c][k];
  }
}

// ---------------------------------------------------------------------------
// Kernel 2: transpose w_proj [1024][1024] -> wtp [n][k]
// ---------------------------------------------------------------------------
__global__ __launch_bounds__(256) void transpose_wp(
    const void* __restrict__ w, bf16* __restrict__ wt, const int* __restrict__ flag) {
  __shared__ __attribute__((aligned(16))) bf16 ls[64][66];
  const int isf = flag[0];
  const int t = threadIdx.x;
  const int r0 = blockIdx.y * 64;
  const int c0 = blockIdx.x * 64;
#pragma unroll
  for (int i = 0; i < 16; ++i) {
    int e = t + i * 256;
    int r = e >> 6, c = e & 63;
    ls[c][r] = __float2bfloat16(rdf(w, (size_t)(r0 + r) * 1024 + c0 + c, isf));
  }
  __syncthreads();
#pragma unroll
  for (int i = 0; i < 16; ++i) {
    int e = t + i * 256;
    int c = e >> 6, r = e & 63;
    wt[(size_t)(c0 + c) * 1024 + r0 + r] = ls[c][r];
  }
}

// ---------------------------------------------------------------------------
// Shared GEMM core (m97 structure): C[128x128] = A[m0..][1024] * Bt[n0..][1024]^T
// BK=32, LDS tiles [128][32] UNPADDED (global_load_lds writes lane-contiguous).
// Per k-iter each wave issues 2 A + 2 B global_load_lds_dwordx4 (16 rows each).
// ---------------------------------------------------------------------------
__device__ __forceinline__ void gemm_core(
    const bf16* __restrict__ A, const bf16* __restrict__ Bt,
    int m0, int n0, f32x4 acc[4][4],
    bf16 lsA[128][32], bf16 lsB[128][32]) {
  const int t = threadIdx.x;
  const int lane = t & 63, w = t >> 6;
  const int quad = lane >> 4, col = lane & 15;
  const int wr = (w >> 1) * 64, wc = (w & 1) * 64;
  // staging source: lane l covers row (l>>2), k-elems (l&3)*8 .. +8
  const int gr = lane >> 2;
  const int gc = (lane & 3) * 8;
  const bf16* gA = A + (size_t)(m0 + w * 32 + gr) * 1024 + gc;
  const bf16* gB = Bt + (size_t)(n0 + w * 32 + gr) * 1024 + gc;
  bf16* dA0 = &lsA[w * 32][0];
  bf16* dA1 = &lsA[w * 32 + 16][0];
  bf16* dB0 = &lsB[w * 32][0];
  bf16* dB1 = &lsB[w * 32 + 16][0];

  for (int kt = 0; kt < 1024; kt += 32) {
    __syncthreads();                       // prev tile's readers done
    gload16(gA + kt, dA0);
    gload16(gA + 16 * 1024 + kt, dA1);
    gload16(gB + kt, dB0);
    gload16(gB + 16 * 1024 + kt, dB1);
    __syncthreads();                       // loads landed (vmcnt drain @ barrier)
    short8 af[4], bfr[4];
#pragma unroll
    for (int i = 0; i < 4; ++i) af[i] = *(const short8*)&lsA[wr + i * 16 + col][quad * 8];
#pragma unroll
    for (int j = 0; j < 4; ++j) bfr[j] = *(const short8*)&lsB[wc + j * 16 + col][quad * 8];
#pragma unroll
    for (int i = 0; i < 4; ++i)
#pragma unroll
      for (int j = 0; j < 4; ++j)
        acc[i][j] = MFMA16(af[i], bfr[j], acc[i][j]);
  }
}

// ---------------------------------------------------------------------------
// Kernel 3: QKV GEMM. A = xc bf16. Scatters q,k -> [b][h][n][dd]; v -> [b][h][dd][n].
// ---------------------------------------------------------------------------
__global__ __launch_bounds__(256) void gemm_qkv(
    const bf16* __restrict__ A, const bf16* __restrict__ Bt,
    const float* __restrict__ bias,
    bf16* __restrict__ qb, bf16* __restrict__ kb, bf16* __restrict__ vb) {
  __shared__ __attribute__((aligned(16))) bf16 lsA[128][32];
  __shared__ __attribute__((aligned(16))) bf16 lsB[128][32];
  const int t = threadIdx.x;
  const int lane = t & 63, w = t >> 6;
  const int quad = lane >> 4, col = lane & 15;
  const int wr = (w >> 1) * 64, wc = (w & 1) * 64;
  const int m0 = blockIdx.y * 128;
  const int n0 = blockIdx.x * 128;
  f32x4 acc[4][4];
  const f32x4 zero = {0.f, 0.f, 0.f, 0.f};
#pragma unroll
  for (int i = 0; i < 4; ++i)
#pragma unroll
    for (int j = 0; j < 4; ++j) acc[i][j] = zero;

  gemm_core(A, Bt, m0, n0, acc, lsA, lsB);

  const int jj = n0 >> 10;
#pragma unroll
  for (int i = 0; i < 4; ++i) {
    int rbase = m0 + wr + i * 16 + quad * 4;
#pragma unroll
    for (int j = 0; j < 4; ++j) {
      int c = n0 + wc + j * 16 + col;
      int cc = c & 1023;
      int h = cc >> 6, dd = cc & 63;
      float bv = bias[c];
#pragma unroll
      for (int r = 0; r < 4; ++r) {
        int m = rbase + r;
        int bb = m >> 10, n = m & 1023;
        bf16 val = __float2bfloat16(acc[i][j][r] + bv);
        size_t bhq = (size_t)(bb * NH + h);
        if (jj == 0)      qb[(bhq * 1024 + n) * 64 + dd] = val;
        else if (jj == 1) kb[(bhq * 1024 + n) * 64 + dd] = val;
        else              vb[(bhq * 64 + dd) * 1024 + n] = val;
      }
    }
  }
}

// ---------------------------------------------------------------------------
// Kernel 4 v2: flash attention with 32x32x16 MFMA, S^T/O^T formulation.
// ---------------------------------------------------------------------------
__global__ __launch_bounds__(256, 4) void attn(
    const bf16* __restrict__ qb, const bf16* __restrict__ kb,
    const bf16* __restrict__ vb, bf16* __restrict__ ob) {
  const int t = threadIdx.x, lane = t & 63, w = t >> 6;
  const int q5 = lane & 31, half = lane >> 5;
  const int bh = blockIdx.y;
  const int bat = bh >> 4, h = bh & 15;
  const int q0 = blockIdx.x * 128;
  const int qrow = q0 + w * 32 + q5;

  __shared__ __attribute__((aligned(16))) bf16 lsK[64][72];  // 9216 B
  __shared__ __attribute__((aligned(16))) bf16 lsV[64][72];  // 9216 B

  const bf16* qp = qb + (size_t)bh * (1024 * 64);
  const bf16* kp = kb + (size_t)bh * (1024 * 64);
  const bf16* vp = vb + (size_t)bh * (64 * 1024);  // [dv][n]

  short8 bq[4];
#pragma unroll
  for (int kk = 0; kk < 4; ++kk)
    bq[kk] = *(const short8*)&qp[(size_t)qrow * 64 + kk * 16 + half * 8];

  float m_run = -1e30f, l_run = 0.f;
  f32x16 po[2];
#pragma unroll
  for (int r = 0; r < 16; ++r) { po[0][r] = 0.f; po[1][r] = 0.f; }

  const int sr = t >> 3;        // 0..31
  const int sc = (t & 7) * 8;   // 0..56

  for (int kt = 0; kt < 1024; kt += 64) {
    int4 g0 = *(const int4*)&kp[(size_t)(kt + sr) * 64 + sc];
    int4 g1 = *(const int4*)&kp[(size_t)(kt + 32 + sr) * 64 + sc];
    int4 g2 = *(const int4*)&vp[(size_t)sr * 1024 + kt + sc];
    int4 g3 = *(const int4*)&vp[(size_t)(32 + sr) * 1024 + kt + sc];
    __syncthreads();
    *(int4*)&lsK[sr][sc] = g0;
    *(int4*)&lsK[32 + sr][sc] = g1;
    *(int4*)&lsV[sr][sc] = g2;
    *(int4*)&lsV[32 + sr][sc] = g3;
    __syncthreads();

    f32x16 st[2];
#pragma unroll
    for (int r = 0; r < 16; ++r) { st[0][r] = 0.f; st[1][r] = 0.f; }
#pragma unroll
    for (int kk = 0; kk < 4; ++kk) {
#pragma unroll
      for (int tj = 0; tj < 2; ++tj) {
        short8 ak = *(const short8*)&lsK[tj * 32 + q5][kk * 16 + half * 8];
        st[tj] = MFMA32(ak, bq[kk], st[tj]);
      }
    }

    float smax = st[0][0];
#pragma unroll
    for (int r = 1; r < 16; ++r) smax = fmaxf(smax, st[0][r]);
#pragma unroll
    for (int r = 0; r < 16; ++r) smax = fmaxf(smax, st[1][r]);
    smax = fmaxf(smax, __shfl_xor(smax, 32));
    float mnew = fmaxf(m_run, smax);
    float alpha = __expf(m_run - mnew);
    m_run = mnew;
    float lsum = 0.f;
#pragma unroll
    for (int tj = 0; tj < 2; ++tj)
#pragma unroll
      for (int r = 0; r < 16; ++r) {
        float p = __expf(st[tj][r] - mnew);
        st[tj][r] = p;
        lsum += p;
      }
    lsum += __shfl_xor(lsum, 32);
    l_run = l_run * alpha + lsum;
#pragma unroll
    for (int r = 0; r < 16; ++r) { po[0][r] *= alpha; po[1][r] *= alpha; }

#pragma unroll
    for (int kk2 = 0; kk2 < 4; ++kk2) {
      const int nbA = 2 * kk2, nbB = 2 * kk2 + 1;
      unsigned int a0 = pk2(st[nbA >> 2][4 * (nbA & 3) + 0], st[nbA >> 2][4 * (nbA & 3) + 1]);
      unsigned int a1 = pk2(st[nbA >> 2][4 * (nbA & 3) + 2], st[nbA >> 2][4 * (nbA & 3) + 3]);
      unsigned int b0 = pk2(st[nbB >> 2][4 * (nbB & 3) + 0], st[nbB >> 2][4 * (nbB & 3) + 1]);
      unsigned int b1 = pk2(st[nbB >> 2][4 * (nbB & 3) + 2], st[nbB >> 2][4 * (nbB & 3) + 3]);
      unsigned int s0 = half ? a0 : b0;
      unsigned int s1 = half ? a1 : b1;
      unsigned int r0 = (unsigned int)__shfl_xor((int)s0, 32);
      unsigned int r1 = (unsigned int)__shfl_xor((int)s1, 32);
      U4S8 fr;
      fr.u.x = half ? r0 : a0;
      fr.u.y = half ? r1 : a1;
      fr.u.z = half ? b0 : r0;
      fr.u.w = half ? b1 : r1;
#pragma unroll
      for (int ti = 0; ti < 2; ++ti) {
        short8 av = *(const short8*)&lsV[ti * 32 + q5][kk2 * 16 + half * 8];
        po[ti] = MFMA32(av, fr.s, po[ti]);
      }
    }
  }

  float inv = 1.0f / (l_run * 32.0f);
  bf16* op = ob + ((size_t)(bat * 1024 + qrow)) * 1024 + h * 64;
#pragma unroll
  for (int ti = 0; ti < 2; ++ti)
#pragma unroll
    for (int g = 0; g < 4; ++g) {
      unsigned int lo = pk2(po[ti][4 * g + 0] * inv, po[ti][4 * g + 1] * inv);
      unsigned int hi = pk2(po[ti][4 * g + 2] * inv, po[ti][4 * g + 3] * inv);
      uint2 u = make_uint2(lo, hi);
      *(uint2*)&op[ti * 32 + g * 8 + half * 4] = u;
    }
}

// ---------------------------------------------------------------------------
// Kernel 5: output projection. A = att bf16, Bt = wtp. OUTPUT: float32.
// ---------------------------------------------------------------------------
__global__ __launch_bounds__(256) void gemm_proj(
    const bf16* __restrict__ A, const bf16* __restrict__ Bt,
    const void* __restrict__ bias, float* __restrict__ out,
    const int* __restrict__ flag) {
  __shared__ __attribute__((aligned(16))) bf16 lsA[128][32];
  __shared__ __attribute__((aligned(16))) bf16 lsB[128][32];
  const int isf = flag[0];
  const int t = threadIdx.x;
  const int lane = t & 63, w = t >> 6;
  const int quad = lane >> 4, col = lane & 15;
  const int wr = (w >> 1) * 64, wc = (w & 1) * 64;
  const int m0 = blockIdx.y * 128;
  const int n0 = blockIdx.x * 128;
  f32x4 acc[4][4];
  const f32x4 zero = {0.f, 0.f, 0.f, 0.f};
#pragma unroll
  for (int i = 0; i < 4; ++i)
#pragma unroll
    for (int j = 0; j < 4; ++j) acc[i][j] = zero;

  gemm_core(A, Bt, m0, n0, acc, lsA, lsB);

#pragma unroll
  for (int i = 0; i < 4; ++i) {
    int rbase = m0 + wr + i * 16 + quad * 4;
#pragma unroll
    for (int j = 0; j < 4; ++j) {
      int c = n0 + wc + j * 16 + col;
      float bv = rdf(bias, c, isf);
#pragma unroll
      for (int r = 0; r < 4; ++r)
        out[(size_t)(rbase + r) * 1024 + c] = acc[i][j][r] + bv;
    }
  }
}

// ---------------------------------------------------------------------------
// Launcher. ws layout (75.5 MB):
//   wt_qkv 6MB | bqp 12KB | wtp 2MB | xc/att 16MB | q 16MB | k 16MB | v 16MB | flag
// ---------------------------------------------------------------------------
extern "C" void kernel_launch(void* const* d_in, const int* in_sizes, int n_in,
                              void* d_out, int out_size, void* d_ws, size_t ws_size,
                              hipStream_t stream) {
  const void* x      = d_in[0];
  const void* w_qkv  = d_in[1];
  const void* b_qkv  = d_in[2];
  const void* w_proj = d_in[3];
  const void* b_proj = d_in[4];
  float* out = (float*)d_out;

  char* ws = (char*)d_ws;
  bf16*  wt_qkv = (bf16*)(ws);
  float* bqp    = (float*)(ws + 6291456);
  bf16*  wtp    = (bf16*)(ws + 6303744);
  bf16*  xc     = (bf16*)(ws + 8400896);    // reused as att after gemm_qkv
  bf16*  q_buf  = (bf16*)(ws + 25178112);
  bf16*  k_buf  = (bf16*)(ws + 41955328);
  bf16*  v_buf  = (bf16*)(ws + 58732544);
  int*   flag   = (int*)(ws + 75509760);
  bf16*  att    = xc;

  detect_dtype<<<1, 64, 0, stream>>>((const unsigned int*)x, flag);
  convert_x<<<4096, 256, 0, stream>>>(x, xc, flag);
  permute_wqkv<<<dim3(16, 16), 256, 0, stream>>>(w_qkv, b_qkv, wt_qkv, bqp, flag);
  transpose_wp<<<dim3(16, 16), 256, 0, stream>>>(w_proj, wtp, flag);
  gemm_qkv<<<dim3(24, 64), 256, 0, stream>>>(xc, wt_qkv, bqp, q_buf, k_buf, v_buf);
  attn<<<dim3(8, 128), 256, 0, stream>>>(q_buf, k_buf, v_buf, att);
  gemm_proj<<<dim3(8, 64), 256, 0, stream>>>(att, wtp, b_proj, out, flag);
}